// Round 2
// baseline (269.678 us; speedup 1.0000x reference)
//
#include <hip/hip_runtime.h>
#include <math.h>
#include <stdint.h>

#define NLEV 16
#define TBL 524288
#define TMASK (TBL - 1)
#define BLOCK 256

struct ResArr { float r[NLEV]; };

__device__ __forceinline__ float silu_f(float v) {
    // x * sigmoid(x); fast exp + fast divide (threshold is ~2% rel)
    return __fdividef(v, 1.0f + __expf(-v));
}

// ---------------- Kernel A: hash-grid encode ----------------
// One thread = (sample, level). level = blockIdx & 15 so that with round-robin
// block->XCD dispatch (XCD ~ blockIdx % 8), all blocks of level l run on
// XCD l%8: each XCD's 4 MB L2 only ever sees 2 level slices (l, l+8).
__global__ void __launch_bounds__(BLOCK)
encode_kernel(const float* __restrict__ x,
              const float* __restrict__ emb,
              float2* __restrict__ enc_ws,
              int nsamp, ResArr res)
{
    const int lvl  = blockIdx.x & (NLEV - 1);
    const int sblk = blockIdx.x >> 4;
    const int t = threadIdx.x;

    __shared__ float sx[BLOCK * 3];
    const float* xblk = x + (size_t)sblk * BLOCK * 3;
    #pragma unroll
    for (int i = 0; i < 3; ++i) sx[t + i * BLOCK] = xblk[t + i * BLOCK];
    __syncthreads();

    const float xn0 = (sx[t * 3 + 0] + 1.0f) * 0.5f;
    const float xn1 = (sx[t * 3 + 1] + 1.0f) * 0.5f;
    const float xn2 = (sx[t * 3 + 2] + 1.0f) * 0.5f;

    const float rs = res.r[lvl];
    const float g0 = xn0 * rs, g1 = xn1 * rs, g2 = xn2 * rs;
    const float f0 = floorf(g0), f1 = floorf(g1), f2 = floorf(g2);
    const float w0 = g0 - f0, w1 = g1 - f1, w2 = g2 - f2;
    const uint32_t u0 = (uint32_t)f0, u1 = (uint32_t)f1, u2 = (uint32_t)f2;
    const uint32_t hb = u0 + u1 * 2654435761u + u2 * 805459861u;
    const float2* tab = (const float2*)emb + (size_t)lvl * TBL;

    const float om0 = 1.0f - w0, om1 = 1.0f - w1, om2 = 1.0f - w2;
    float e0 = 0.0f, e1 = 0.0f;
    #pragma unroll
    for (int c = 0; c < 8; ++c) {
        const uint32_t cb0 = (c >> 2) & 1, cb1 = (c >> 1) & 1, cb2 = c & 1;
        uint32_t h = hb;
        if (cb0) h += 1u;
        if (cb1) h += 2654435761u;
        if (cb2) h += 805459861u;
        h &= TMASK;
        const float2 v = tab[h];
        float wt = (cb0 ? w0 : om0) * (cb1 ? w1 : om1);
        wt *= (cb2 ? w2 : om2);
        e0 = fmaf(wt, v.x, e0);
        e1 = fmaf(wt, v.y, e1);
    }

    const int s = sblk * BLOCK + t;
    union { float2 f; unsigned long long u; } pk;
    pk.f.x = e0; pk.f.y = e1;
    // streaming store: don't evict table lines from L2
    __builtin_nontemporal_store(pk.u, (unsigned long long*)&enc_ws[(size_t)lvl * nsamp + s]);
}

// ---------------- Kernel B: MLP 32 -> 64 -> 64 -> 1 ----------------
__global__ void __launch_bounds__(BLOCK)
mlp_kernel(const float2* __restrict__ enc_ws,
           const float* __restrict__ W1,
           const float* __restrict__ b1,
           const float* __restrict__ W2,
           const float* __restrict__ b2,
           const float* __restrict__ Wout,
           const float* __restrict__ bout,
           float* __restrict__ out, int nsamp)
{
    const int t = threadIdx.x;
    const int s = blockIdx.x * BLOCK + t;

    float enc[2 * NLEV];
    #pragma unroll
    for (int l = 0; l < NLEV; ++l) {
        const float2 v = enc_ws[(size_t)l * nsamp + s];  // coalesced per level
        enc[2 * l + 0] = v.x;
        enc[2 * l + 1] = v.y;
    }

    float h1[64];
    #pragma unroll
    for (int i = 0; i < 64; ++i) {
        float acc = b1[i];
        #pragma unroll
        for (int k = 0; k < 32; ++k)
            acc = fmaf(enc[k], W1[i * 32 + k], acc);
        h1[i] = silu_f(acc);
    }

    float o = bout[0];
    #pragma unroll
    for (int i = 0; i < 64; ++i) {
        float acc = b2[i];
        #pragma unroll
        for (int k = 0; k < 64; ++k)
            acc = fmaf(h1[k], W2[i * 64 + k], acc);
        o = fmaf(silu_f(acc), Wout[i], o);
    }

    out[s] = o;
}

// ---------------- Fallback: V1 monolithic (if ws too small) ----------------
__global__ void __launch_bounds__(BLOCK)
hashgrid_mlp_kernel(const float* __restrict__ x,
                    const float* __restrict__ emb,
                    const float* __restrict__ W1,
                    const float* __restrict__ b1,
                    const float* __restrict__ W2,
                    const float* __restrict__ b2,
                    const float* __restrict__ Wout,
                    const float* __restrict__ bout,
                    float* __restrict__ out,
                    ResArr res)
{
    __shared__ float sx[BLOCK * 3];
    const int t = threadIdx.x;
    const int base = blockIdx.x * BLOCK;

    const float* xblk = x + (size_t)base * 3;
    #pragma unroll
    for (int i = 0; i < 3; ++i) sx[t + i * BLOCK] = xblk[t + i * BLOCK];
    __syncthreads();

    const float xn0 = (sx[t * 3 + 0] + 1.0f) * 0.5f;
    const float xn1 = (sx[t * 3 + 1] + 1.0f) * 0.5f;
    const float xn2 = (sx[t * 3 + 2] + 1.0f) * 0.5f;

    float enc[2 * NLEV];

    #pragma unroll
    for (int l = 0; l < NLEV; ++l) {
        const float rs = res.r[l];
        const float g0 = xn0 * rs, g1 = xn1 * rs, g2 = xn2 * rs;
        const float f0 = floorf(g0), f1 = floorf(g1), f2 = floorf(g2);
        const float w0 = g0 - f0, w1 = g1 - f1, w2 = g2 - f2;
        const uint32_t u0 = (uint32_t)f0, u1 = (uint32_t)f1, u2 = (uint32_t)f2;
        const uint32_t hb = u0 + u1 * 2654435761u + u2 * 805459861u;
        const float2* tab = (const float2*)emb + (size_t)l * TBL;

        const float om0 = 1.0f - w0, om1 = 1.0f - w1, om2 = 1.0f - w2;
        float e0 = 0.0f, e1 = 0.0f;
        #pragma unroll
        for (int c = 0; c < 8; ++c) {
            const uint32_t cb0 = (c >> 2) & 1, cb1 = (c >> 1) & 1, cb2 = c & 1;
            uint32_t h = hb;
            if (cb0) h += 1u;
            if (cb1) h += 2654435761u;
            if (cb2) h += 805459861u;
            h &= TMASK;
            const float2 v = tab[h];
            float wt = (cb0 ? w0 : om0) * (cb1 ? w1 : om1);
            wt *= (cb2 ? w2 : om2);
            e0 = fmaf(wt, v.x, e0);
            e1 = fmaf(wt, v.y, e1);
        }
        enc[2 * l + 0] = e0;
        enc[2 * l + 1] = e1;
    }

    float h1[64];
    #pragma unroll
    for (int i = 0; i < 64; ++i) {
        float acc = b1[i];
        #pragma unroll
        for (int k = 0; k < 32; ++k)
            acc = fmaf(enc[k], W1[i * 32 + k], acc);
        h1[i] = silu_f(acc);
    }

    float o = bout[0];
    #pragma unroll
    for (int i = 0; i < 64; ++i) {
        float acc = b2[i];
        #pragma unroll
        for (int k = 0; k < 64; ++k)
            acc = fmaf(h1[k], W2[i * 64 + k], acc);
        o = fmaf(silu_f(acc), Wout[i], o);
    }

    out[base + t] = o;
}

extern "C" void kernel_launch(void* const* d_in, const int* in_sizes, int n_in,
                              void* d_out, int out_size, void* d_ws, size_t ws_size,
                              hipStream_t stream) {
    const float* x    = (const float*)d_in[0];
    const float* emb  = (const float*)d_in[1];
    const float* W1   = (const float*)d_in[2];
    const float* b1   = (const float*)d_in[3];
    const float* W2   = (const float*)d_in[4];
    const float* b2   = (const float*)d_in[5];
    const float* Wout = (const float*)d_in[6];
    const float* bout = (const float*)d_in[7];
    float* out = (float*)d_out;

    ResArr res;
    const double lg0 = log(16.0), lg1 = log(2048.0);
    for (int i = 0; i < NLEV; ++i)
        res.r[i] = (float)exp(lg0 + (lg1 - lg0) * (double)i / 15.0);

    const int n = in_sizes[0] / 3;                     // 262144 samples
    const size_t ws_needed = (size_t)n * NLEV * sizeof(float2);

    if (ws_size >= ws_needed) {
        float2* enc_ws = (float2*)d_ws;
        dim3 gridA((n / BLOCK) * NLEV);
        encode_kernel<<<gridA, BLOCK, 0, stream>>>(x, emb, enc_ws, n, res);
        dim3 gridB(n / BLOCK);
        mlp_kernel<<<gridB, BLOCK, 0, stream>>>(enc_ws, W1, b1, W2, b2,
                                                Wout, bout, out, n);
    } else {
        dim3 grid(n / BLOCK);
        hashgrid_mlp_kernel<<<grid, BLOCK, 0, stream>>>(x, emb, W1, b1, W2, b2,
                                                        Wout, bout, out, res);
    }
}

// Round 3
// 241.739 us; speedup vs baseline: 1.1156x; 1.1156x over previous
//
#include <hip/hip_runtime.h>
#include <math.h>
#include <stdint.h>

#define NLEV 16
#define TBL 524288
#define TMASK (TBL - 1)
#define BLOCK 256
#define SPT 2            // samples per thread in encode

struct ResArr { float r[NLEV]; };

__device__ __forceinline__ float silu_f(float v) {
    return __fdividef(v, 1.0f + __expf(-v));
}

// ---------------- Kernel A: hash-grid encode ----------------
// Phase-split level->XCD mapping: grid = 2 * 8 * CHUNKS blocks.
// First half: levels 0-7, lvl = blockIdx%8  -> XCD i serves only level i.
// Second half: levels 8-15 likewise. Each XCD's 4MB L2 holds exactly one
// level slice (4MB) at a time -> table reads become L2 hits after first touch.
__global__ void __launch_bounds__(BLOCK)
encode_kernel(const float* __restrict__ x,
              const float* __restrict__ emb,
              float2* __restrict__ enc_ws,
              int nsamp, ResArr res)
{
    const int bid  = blockIdx.x;
    const int half = gridDim.x >> 1;
    int lvl, chunk;
    if (bid < half) { lvl = bid & 7;        chunk = bid >> 3; }
    else            { lvl = 8 + ((bid - half) & 7); chunk = (bid - half) >> 3; }

    const int t  = threadIdx.x;
    const int s0 = chunk * (BLOCK * SPT) + t;
    const float rs = res.r[lvl];
    const float2* tab = (const float2*)emb + (size_t)lvl * TBL;

    uint32_t idx[SPT][8];
    float w0[SPT], w1[SPT], w2[SPT];

    #pragma unroll
    for (int p = 0; p < SPT; ++p) {
        const int s = s0 + p * BLOCK;
        // nontemporal: x stream must not evict table lines from L2
        const float xv0 = __builtin_nontemporal_load(&x[(size_t)s * 3 + 0]);
        const float xv1 = __builtin_nontemporal_load(&x[(size_t)s * 3 + 1]);
        const float xv2 = __builtin_nontemporal_load(&x[(size_t)s * 3 + 2]);
        const float g0 = (xv0 + 1.0f) * 0.5f * rs;
        const float g1 = (xv1 + 1.0f) * 0.5f * rs;
        const float g2 = (xv2 + 1.0f) * 0.5f * rs;
        const float f0 = floorf(g0), f1 = floorf(g1), f2 = floorf(g2);
        w0[p] = g0 - f0; w1[p] = g1 - f1; w2[p] = g2 - f2;
        const uint32_t hb = (uint32_t)f0 + (uint32_t)f1 * 2654435761u
                          + (uint32_t)f2 * 805459861u;
        #pragma unroll
        for (int c = 0; c < 8; ++c) {
            const uint32_t cb0 = (c >> 2) & 1, cb1 = (c >> 1) & 1, cb2 = c & 1;
            uint32_t h = hb;
            if (cb0) h += 1u;
            if (cb1) h += 2654435761u;
            if (cb2) h += 805459861u;
            idx[p][c] = h & TMASK;
        }
    }

    // issue all gathers (independent -> all in flight together)
    float2 vals[SPT][8];
    #pragma unroll
    for (int p = 0; p < SPT; ++p)
        #pragma unroll
        for (int c = 0; c < 8; ++c)
            vals[p][c] = tab[idx[p][c]];

    #pragma unroll
    for (int p = 0; p < SPT; ++p) {
        const float om0 = 1.0f - w0[p], om1 = 1.0f - w1[p], om2 = 1.0f - w2[p];
        float e0 = 0.0f, e1 = 0.0f;
        #pragma unroll
        for (int c = 0; c < 8; ++c) {
            const uint32_t cb0 = (c >> 2) & 1, cb1 = (c >> 1) & 1, cb2 = c & 1;
            float wt = (cb0 ? w0[p] : om0) * (cb1 ? w1[p] : om1);
            wt *= (cb2 ? w2[p] : om2);
            e0 = fmaf(wt, vals[p][c].x, e0);
            e1 = fmaf(wt, vals[p][c].y, e1);
        }
        const int s = s0 + p * BLOCK;
        union { float2 f; unsigned long long u; } pk;
        pk.f.x = e0; pk.f.y = e1;
        __builtin_nontemporal_store(pk.u,
            (unsigned long long*)&enc_ws[(size_t)lvl * nsamp + s]);
    }
}

// ---------------- Kernel B: MLP 32 -> 64 -> 64 -> 1 ----------------
__global__ void __launch_bounds__(BLOCK)
mlp_kernel(const float2* __restrict__ enc_ws,
           const float* __restrict__ W1,
           const float* __restrict__ b1,
           const float* __restrict__ W2,
           const float* __restrict__ b2,
           const float* __restrict__ Wout,
           const float* __restrict__ bout,
           float* __restrict__ out, int nsamp)
{
    const int t = threadIdx.x;
    const int s = blockIdx.x * BLOCK + t;

    float enc[2 * NLEV];
    #pragma unroll
    for (int l = 0; l < NLEV; ++l) {
        const float2 v = enc_ws[(size_t)l * nsamp + s];  // coalesced per level
        enc[2 * l + 0] = v.x;
        enc[2 * l + 1] = v.y;
    }

    float h1[64];
    #pragma unroll
    for (int i = 0; i < 64; ++i) {
        float acc = b1[i];
        #pragma unroll
        for (int k = 0; k < 32; ++k)
            acc = fmaf(enc[k], W1[i * 32 + k], acc);
        h1[i] = silu_f(acc);
    }

    float o = bout[0];
    #pragma unroll
    for (int i = 0; i < 64; ++i) {
        float acc = b2[i];
        #pragma unroll
        for (int k = 0; k < 64; ++k)
            acc = fmaf(h1[k], W2[i * 64 + k], acc);
        o = fmaf(silu_f(acc), Wout[i], o);
    }

    out[s] = o;
}

// ---------------- Fallback: monolithic (if ws too small) ----------------
__global__ void __launch_bounds__(BLOCK)
hashgrid_mlp_kernel(const float* __restrict__ x,
                    const float* __restrict__ emb,
                    const float* __restrict__ W1,
                    const float* __restrict__ b1,
                    const float* __restrict__ W2,
                    const float* __restrict__ b2,
                    const float* __restrict__ Wout,
                    const float* __restrict__ bout,
                    float* __restrict__ out,
                    ResArr res)
{
    const int t = threadIdx.x;
    const int s = blockIdx.x * BLOCK + t;

    const float xn0 = (x[(size_t)s * 3 + 0] + 1.0f) * 0.5f;
    const float xn1 = (x[(size_t)s * 3 + 1] + 1.0f) * 0.5f;
    const float xn2 = (x[(size_t)s * 3 + 2] + 1.0f) * 0.5f;

    float enc[2 * NLEV];
    #pragma unroll
    for (int l = 0; l < NLEV; ++l) {
        const float rs = res.r[l];
        const float g0 = xn0 * rs, g1 = xn1 * rs, g2 = xn2 * rs;
        const float f0 = floorf(g0), f1 = floorf(g1), f2 = floorf(g2);
        const float w0 = g0 - f0, w1 = g1 - f1, w2 = g2 - f2;
        const uint32_t hb = (uint32_t)f0 + (uint32_t)f1 * 2654435761u
                          + (uint32_t)f2 * 805459861u;
        const float2* tab = (const float2*)emb + (size_t)l * TBL;
        const float om0 = 1.0f - w0, om1 = 1.0f - w1, om2 = 1.0f - w2;
        float e0 = 0.0f, e1 = 0.0f;
        #pragma unroll
        for (int c = 0; c < 8; ++c) {
            const uint32_t cb0 = (c >> 2) & 1, cb1 = (c >> 1) & 1, cb2 = c & 1;
            uint32_t h = hb;
            if (cb0) h += 1u;
            if (cb1) h += 2654435761u;
            if (cb2) h += 805459861u;
            h &= TMASK;
            const float2 v = tab[h];
            float wt = (cb0 ? w0 : om0) * (cb1 ? w1 : om1);
            wt *= (cb2 ? w2 : om2);
            e0 = fmaf(wt, v.x, e0);
            e1 = fmaf(wt, v.y, e1);
        }
        enc[2 * l + 0] = e0;
        enc[2 * l + 1] = e1;
    }

    float h1[64];
    #pragma unroll
    for (int i = 0; i < 64; ++i) {
        float acc = b1[i];
        #pragma unroll
        for (int k = 0; k < 32; ++k)
            acc = fmaf(enc[k], W1[i * 32 + k], acc);
        h1[i] = silu_f(acc);
    }
    float o = bout[0];
    #pragma unroll
    for (int i = 0; i < 64; ++i) {
        float acc = b2[i];
        #pragma unroll
        for (int k = 0; k < 64; ++k)
            acc = fmaf(h1[k], W2[i * 64 + k], acc);
        o = fmaf(silu_f(acc), Wout[i], o);
    }
    out[s] = o;
}

extern "C" void kernel_launch(void* const* d_in, const int* in_sizes, int n_in,
                              void* d_out, int out_size, void* d_ws, size_t ws_size,
                              hipStream_t stream) {
    const float* x    = (const float*)d_in[0];
    const float* emb  = (const float*)d_in[1];
    const float* W1   = (const float*)d_in[2];
    const float* b1   = (const float*)d_in[3];
    const float* W2   = (const float*)d_in[4];
    const float* b2   = (const float*)d_in[5];
    const float* Wout = (const float*)d_in[6];
    const float* bout = (const float*)d_in[7];
    float* out = (float*)d_out;

    ResArr res;
    const double lg0 = log(16.0), lg1 = log(2048.0);
    for (int i = 0; i < NLEV; ++i)
        res.r[i] = (float)exp(lg0 + (lg1 - lg0) * (double)i / 15.0);

    const int n = in_sizes[0] / 3;                     // 262144 samples
    const size_t ws_needed = (size_t)n * NLEV * sizeof(float2);

    if (ws_size >= ws_needed) {
        float2* enc_ws = (float2*)d_ws;
        const int chunks = n / (BLOCK * SPT);          // 512
        dim3 gridA(2 * 8 * chunks);                    // 8192 blocks, phase-split
        encode_kernel<<<gridA, BLOCK, 0, stream>>>(x, emb, enc_ws, n, res);
        dim3 gridB(n / BLOCK);
        mlp_kernel<<<gridB, BLOCK, 0, stream>>>(enc_ws, W1, b1, W2, b2,
                                                Wout, bout, out, n);
    } else {
        dim3 grid(n / BLOCK);
        hashgrid_mlp_kernel<<<grid, BLOCK, 0, stream>>>(x, emb, W1, b1, W2, b2,
                                                        Wout, bout, out, res);
    }
}

// Round 5
// 192.696 us; speedup vs baseline: 1.3995x; 1.2545x over previous
//
#include <hip/hip_runtime.h>
#include <math.h>
#include <stdint.h>

#define NLEV 16
#define TBL 524288
#define TMASK (TBL - 1)
#define BLOCK 256
#define SPT 2            // samples per thread in encode
#define P1 2654435761u
#define P2 805459861u

struct ResArr { float r[NLEV]; };

typedef __attribute__((ext_vector_type(4))) float f32x4;
// 8B-aligned 16B load (table entries are float2-aligned; dwordx4 only needs dword align on gfx950)
struct __attribute__((packed, aligned(8))) f4wrap { f32x4 v; };

__device__ __forceinline__ float silu_f(float v) {
    return __fdividef(v, 1.0f + __expf(-v));
}

// ---------------- Kernel A: hash-grid encode ----------------
// Phase-split level->XCD mapping (each XCD's L2 holds exactly one 4MB slice),
// plus corner pairing: corners c and c+4 differ only in the dim0 bit whose
// hash coefficient is 1 -> table indices h and h+1 -> one dwordx4 covers both.
__global__ void __launch_bounds__(BLOCK)
encode_kernel(const float* __restrict__ x,
              const float* __restrict__ emb,
              float2* __restrict__ enc_ws,
              int nsamp, ResArr res)
{
    const int bid  = blockIdx.x;
    const int half = gridDim.x >> 1;
    int lvl, chunk;
    if (bid < half) { lvl = bid & 7;               chunk = bid >> 3; }
    else            { lvl = 8 + ((bid - half) & 7); chunk = (bid - half) >> 3; }

    const int t  = threadIdx.x;
    const int s0 = chunk * (BLOCK * SPT) + t;
    const float rs = res.r[lvl];
    const float* tabf = emb + (size_t)lvl * TBL * 2;   // float view of level slice

    uint32_t i0[SPT][4];
    float w0[SPT], w1[SPT], w2[SPT];
    uint32_t bad = 0;

    #pragma unroll
    for (int p = 0; p < SPT; ++p) {
        const int s = s0 + p * BLOCK;
        const float xv0 = __builtin_nontemporal_load(&x[(size_t)s * 3 + 0]);
        const float xv1 = __builtin_nontemporal_load(&x[(size_t)s * 3 + 1]);
        const float xv2 = __builtin_nontemporal_load(&x[(size_t)s * 3 + 2]);
        const float g0 = (xv0 + 1.0f) * 0.5f * rs;
        const float g1 = (xv1 + 1.0f) * 0.5f * rs;
        const float g2 = (xv2 + 1.0f) * 0.5f * rs;
        const float f0 = floorf(g0), f1 = floorf(g1), f2 = floorf(g2);
        w0[p] = g0 - f0; w1[p] = g1 - f1; w2[p] = g2 - f2;
        const uint32_t hb = (uint32_t)f0 + (uint32_t)f1 * P1 + (uint32_t)f2 * P2;
        #pragma unroll
        for (int q = 0; q < 4; ++q) {     // q: (dim1,dim2) corner bits; dim0 paired
            uint32_t h = hb;
            if ((q >> 1) & 1) h += P1;
            if (q & 1)        h += P2;
            i0[p][q] = h & TMASK;
            bad |= (uint32_t)(i0[p][q] == TMASK);
        }
    }

    f32x4 v[SPT][4];
    if (__builtin_expect(__any((int)bad), 0)) {
        // rare wrap path: second entry of a pair is index 0
        #pragma unroll
        for (int p = 0; p < SPT; ++p)
            #pragma unroll
            for (int q = 0; q < 4; ++q) {
                const uint32_t a = i0[p][q];
                const uint32_t b = (a + 1u) & TMASK;
                const float2 lo = *(const float2*)(tabf + 2 * (size_t)a);
                const float2 hi = *(const float2*)(tabf + 2 * (size_t)b);
                v[p][q] = f32x4{lo.x, lo.y, hi.x, hi.y};
            }
    } else {
        // fast path: all 8 pair-loads independent & in flight together
        #pragma unroll
        for (int p = 0; p < SPT; ++p)
            #pragma unroll
            for (int q = 0; q < 4; ++q)
                v[p][q] = ((const f4wrap*)(tabf + 2 * (size_t)i0[p][q]))->v;
    }

    #pragma unroll
    for (int p = 0; p < SPT; ++p) {
        const float om0 = 1.0f - w0[p], om1 = 1.0f - w1[p], om2 = 1.0f - w2[p];
        float e0 = 0.0f, e1 = 0.0f;
        #pragma unroll
        for (int q = 0; q < 4; ++q) {
            float wb = (((q >> 1) & 1) ? w1[p] : om1) * ((q & 1) ? w2[p] : om2);
            const float c0 = om0 * wb;          // corner with dim0 bit = 0
            const float c1 = w0[p] * wb;        // corner with dim0 bit = 1
            e0 = fmaf(c0, v[p][q].x, fmaf(c1, v[p][q].z, e0));
            e1 = fmaf(c0, v[p][q].y, fmaf(c1, v[p][q].w, e1));
        }
        const int s = s0 + p * BLOCK;
        union { float2 f; unsigned long long u; } pk;
        pk.f.x = e0; pk.f.y = e1;
        __builtin_nontemporal_store(pk.u,
            (unsigned long long*)&enc_ws[(size_t)lvl * nsamp + s]);
    }
}

// ---------------- Kernel B: MLP 32 -> 64 -> 64 -> 1 ----------------
__global__ void __launch_bounds__(BLOCK)
mlp_kernel(const float2* __restrict__ enc_ws,
           const float* __restrict__ W1,
           const float* __restrict__ b1,
           const float* __restrict__ W2,
           const float* __restrict__ b2,
           const float* __restrict__ Wout,
           const float* __restrict__ bout,
           float* __restrict__ out, int nsamp)
{
    const int t = threadIdx.x;
    const int s = blockIdx.x * BLOCK + t;

    float enc[2 * NLEV];
    #pragma unroll
    for (int l = 0; l < NLEV; ++l) {
        const float2 v = enc_ws[(size_t)l * nsamp + s];  // coalesced per level
        enc[2 * l + 0] = v.x;
        enc[2 * l + 1] = v.y;
    }

    float h1[64];
    #pragma unroll
    for (int i = 0; i < 64; ++i) {
        float acc = b1[i];
        #pragma unroll
        for (int k = 0; k < 32; ++k)
            acc = fmaf(enc[k], W1[i * 32 + k], acc);
        h1[i] = silu_f(acc);
    }

    float o = bout[0];
    #pragma unroll
    for (int i = 0; i < 64; ++i) {
        float acc = b2[i];
        #pragma unroll
        for (int k = 0; k < 64; ++k)
            acc = fmaf(h1[k], W2[i * 64 + k], acc);
        o = fmaf(silu_f(acc), Wout[i], o);
    }

    out[s] = o;
}

// ---------------- Fallback: monolithic (if ws too small) ----------------
__global__ void __launch_bounds__(BLOCK)
hashgrid_mlp_kernel(const float* __restrict__ x,
                    const float* __restrict__ emb,
                    const float* __restrict__ W1,
                    const float* __restrict__ b1,
                    const float* __restrict__ W2,
                    const float* __restrict__ b2,
                    const float* __restrict__ Wout,
                    const float* __restrict__ bout,
                    float* __restrict__ out,
                    ResArr res)
{
    const int t = threadIdx.x;
    const int s = blockIdx.x * BLOCK + t;

    const float xn0 = (x[(size_t)s * 3 + 0] + 1.0f) * 0.5f;
    const float xn1 = (x[(size_t)s * 3 + 1] + 1.0f) * 0.5f;
    const float xn2 = (x[(size_t)s * 3 + 2] + 1.0f) * 0.5f;

    float enc[2 * NLEV];
    #pragma unroll
    for (int l = 0; l < NLEV; ++l) {
        const float rs = res.r[l];
        const float g0 = xn0 * rs, g1 = xn1 * rs, g2 = xn2 * rs;
        const float f0 = floorf(g0), f1 = floorf(g1), f2 = floorf(g2);
        const float w0 = g0 - f0, w1 = g1 - f1, w2 = g2 - f2;
        const uint32_t hb = (uint32_t)f0 + (uint32_t)f1 * P1 + (uint32_t)f2 * P2;
        const float2* tab = (const float2*)emb + (size_t)l * TBL;
        const float om0 = 1.0f - w0, om1 = 1.0f - w1, om2 = 1.0f - w2;
        float e0 = 0.0f, e1 = 0.0f;
        #pragma unroll
        for (int c = 0; c < 8; ++c) {
            const uint32_t cb0 = (c >> 2) & 1, cb1 = (c >> 1) & 1, cb2 = c & 1;
            uint32_t h = hb;
            if (cb0) h += 1u;
            if (cb1) h += P1;
            if (cb2) h += P2;
            h &= TMASK;
            const float2 vv = tab[h];
            float wt = (cb0 ? w0 : om0) * (cb1 ? w1 : om1);
            wt *= (cb2 ? w2 : om2);
            e0 = fmaf(wt, vv.x, e0);
            e1 = fmaf(wt, vv.y, e1);
        }
        enc[2 * l + 0] = e0;
        enc[2 * l + 1] = e1;
    }

    float h1[64];
    #pragma unroll
    for (int i = 0; i < 64; ++i) {
        float acc = b1[i];
        #pragma unroll
        for (int k = 0; k < 32; ++k)
            acc = fmaf(enc[k], W1[i * 32 + k], acc);
        h1[i] = silu_f(acc);
    }
    float o = bout[0];
    #pragma unroll
    for (int i = 0; i < 64; ++i) {
        float acc = b2[i];
        #pragma unroll
        for (int k = 0; k < 64; ++k)
            acc = fmaf(h1[k], W2[i * 64 + k], acc);
        o = fmaf(silu_f(acc), Wout[i], o);
    }
    out[s] = o;
}

extern "C" void kernel_launch(void* const* d_in, const int* in_sizes, int n_in,
                              void* d_out, int out_size, void* d_ws, size_t ws_size,
                              hipStream_t stream) {
    const float* x    = (const float*)d_in[0];
    const float* emb  = (const float*)d_in[1];
    const float* W1   = (const float*)d_in[2];
    const float* b1   = (const float*)d_in[3];
    const float* W2   = (const float*)d_in[4];
    const float* b2   = (const float*)d_in[5];
    const float* Wout = (const float*)d_in[6];
    const float* bout = (const float*)d_in[7];
    float* out = (float*)d_out;

    ResArr res;
    const double lg0 = log(16.0), lg1 = log(2048.0);
    for (int i = 0; i < NLEV; ++i)
        res.r[i] = (float)exp(lg0 + (lg1 - lg0) * (double)i / 15.0);

    const int n = in_sizes[0] / 3;                     // 262144 samples
    const size_t ws_needed = (size_t)n * NLEV * sizeof(float2);

    if (ws_size >= ws_needed) {
        float2* enc_ws = (float2*)d_ws;
        const int chunks = n / (BLOCK * SPT);          // 512
        dim3 gridA(2 * 8 * chunks);                    // 8192 blocks, phase-split
        encode_kernel<<<gridA, BLOCK, 0, stream>>>(x, emb, enc_ws, n, res);
        dim3 gridB(n / BLOCK);
        mlp_kernel<<<gridB, BLOCK, 0, stream>>>(enc_ws, W1, b1, W2, b2,
                                                Wout, bout, out, n);
    } else {
        dim3 grid(n / BLOCK);
        hashgrid_mlp_kernel<<<grid, BLOCK, 0, stream>>>(x, emb, W1, b1, W2, b2,
                                                        Wout, bout, out, res);
    }
}

// Round 6
// 190.426 us; speedup vs baseline: 1.4162x; 1.0119x over previous
//
#include <hip/hip_runtime.h>
#include <math.h>
#include <stdint.h>

#define NLEV 16
#define TBL 524288
#define TMASK (TBL - 1)
#define BLOCK 256
#define SPT 4            // samples per thread in encode
#define MSPT 2           // samples per thread in MLP
#define P1 2654435761u
#define P2 805459861u

struct ResArr { float r[NLEV]; };

typedef __attribute__((ext_vector_type(4))) float f32x4;
// 8B-aligned 16B load (table entries are float2-aligned; dwordx4 only needs dword align)
struct __attribute__((packed, aligned(8))) f4wrap { f32x4 v; };

__device__ __forceinline__ float silu_f(float v) {
    return __fdividef(v, 1.0f + __expf(-v));
}

// ---------------- Kernel A: hash-grid encode ----------------
// Phase-split level->XCD mapping (each XCD's L2 holds exactly one 4MB slice),
// corner pairing (dim0 hash coeff == 1 -> corners c,c+4 are adjacent entries:
// one dwordx4 covers both), SPT=4 samples/thread for 16 loads in flight.
__global__ void __launch_bounds__(BLOCK)
encode_kernel(const float* __restrict__ x,
              const float* __restrict__ emb,
              float2* __restrict__ enc_ws,
              int nsamp, ResArr res)
{
    const int bid  = blockIdx.x;
    const int half = gridDim.x >> 1;
    int lvl, chunk;
    if (bid < half) { lvl = bid & 7;               chunk = bid >> 3; }
    else            { lvl = 8 + ((bid - half) & 7); chunk = (bid - half) >> 3; }

    const int t  = threadIdx.x;
    const int s0 = chunk * (BLOCK * SPT) + t;
    const float rs = res.r[lvl];
    const float* tabf = emb + (size_t)lvl * TBL * 2;   // float view of level slice

    uint32_t i0[SPT][4];
    float w0[SPT], w1[SPT], w2[SPT];
    uint32_t bad = 0;

    #pragma unroll
    for (int p = 0; p < SPT; ++p) {
        const int s = s0 + p * BLOCK;
        const float xv0 = __builtin_nontemporal_load(&x[(size_t)s * 3 + 0]);
        const float xv1 = __builtin_nontemporal_load(&x[(size_t)s * 3 + 1]);
        const float xv2 = __builtin_nontemporal_load(&x[(size_t)s * 3 + 2]);
        const float g0 = (xv0 + 1.0f) * 0.5f * rs;
        const float g1 = (xv1 + 1.0f) * 0.5f * rs;
        const float g2 = (xv2 + 1.0f) * 0.5f * rs;
        const float f0 = floorf(g0), f1 = floorf(g1), f2 = floorf(g2);
        w0[p] = g0 - f0; w1[p] = g1 - f1; w2[p] = g2 - f2;
        const uint32_t hb = (uint32_t)f0 + (uint32_t)f1 * P1 + (uint32_t)f2 * P2;
        #pragma unroll
        for (int q = 0; q < 4; ++q) {     // q: (dim1,dim2) corner bits; dim0 paired
            uint32_t h = hb;
            if ((q >> 1) & 1) h += P1;
            if (q & 1)        h += P2;
            i0[p][q] = h & TMASK;
            bad |= (uint32_t)(i0[p][q] == TMASK);
        }
    }

    f32x4 v[SPT][4];
    if (__builtin_expect(__any((int)bad), 0)) {
        // rare wrap path: second entry of a pair is index 0
        #pragma unroll
        for (int p = 0; p < SPT; ++p)
            #pragma unroll
            for (int q = 0; q < 4; ++q) {
                const uint32_t a = i0[p][q];
                const uint32_t b = (a + 1u) & TMASK;
                const float2 lo = *(const float2*)(tabf + 2 * (size_t)a);
                const float2 hi = *(const float2*)(tabf + 2 * (size_t)b);
                v[p][q] = f32x4{lo.x, lo.y, hi.x, hi.y};
            }
    } else {
        // fast path: all 16 pair-loads independent & in flight together
        #pragma unroll
        for (int p = 0; p < SPT; ++p)
            #pragma unroll
            for (int q = 0; q < 4; ++q)
                v[p][q] = ((const f4wrap*)(tabf + 2 * (size_t)i0[p][q]))->v;
    }

    #pragma unroll
    for (int p = 0; p < SPT; ++p) {
        const float om0 = 1.0f - w0[p], om1 = 1.0f - w1[p], om2 = 1.0f - w2[p];
        float e0 = 0.0f, e1 = 0.0f;
        #pragma unroll
        for (int q = 0; q < 4; ++q) {
            float wb = (((q >> 1) & 1) ? w1[p] : om1) * ((q & 1) ? w2[p] : om2);
            const float c0 = om0 * wb;          // corner with dim0 bit = 0
            const float c1 = w0[p] * wb;        // corner with dim0 bit = 1
            e0 = fmaf(c0, v[p][q].x, fmaf(c1, v[p][q].z, e0));
            e1 = fmaf(c0, v[p][q].y, fmaf(c1, v[p][q].w, e1));
        }
        const int s = s0 + p * BLOCK;
        union { float2 f; unsigned long long u; } pk;
        pk.f.x = e0; pk.f.y = e1;
        __builtin_nontemporal_store(pk.u,
            (unsigned long long*)&enc_ws[(size_t)lvl * nsamp + s]);
    }
}

// ---------------- Kernel B: MLP 32 -> 64 -> 64 -> 1 ----------------
// 2 samples/thread: every wave-uniform weight s_load feeds two FMA chains
// (halves SMEM stall per FLOP, doubles ILP).
__global__ void __launch_bounds__(BLOCK)
mlp_kernel(const float2* __restrict__ enc_ws,
           const float* __restrict__ W1,
           const float* __restrict__ b1,
           const float* __restrict__ W2,
           const float* __restrict__ b2,
           const float* __restrict__ Wout,
           const float* __restrict__ bout,
           float* __restrict__ out, int nsamp)
{
    const int t  = threadIdx.x;
    const int sA = blockIdx.x * (BLOCK * MSPT) + t;
    const int sB = sA + BLOCK;

    float encA[2 * NLEV], encB[2 * NLEV];
    #pragma unroll
    for (int l = 0; l < NLEV; ++l) {
        const float2 va = enc_ws[(size_t)l * nsamp + sA];  // coalesced per level
        const float2 vb = enc_ws[(size_t)l * nsamp + sB];
        encA[2 * l] = va.x; encA[2 * l + 1] = va.y;
        encB[2 * l] = vb.x; encB[2 * l + 1] = vb.y;
    }

    float hA[64], hB[64];
    #pragma unroll
    for (int i = 0; i < 64; ++i) {
        const float bi = b1[i];
        float a = bi, b = bi;
        #pragma unroll
        for (int k = 0; k < 32; ++k) {
            const float w = W1[i * 32 + k];
            a = fmaf(encA[k], w, a);
            b = fmaf(encB[k], w, b);
        }
        hA[i] = silu_f(a);
        hB[i] = silu_f(b);
    }

    float oA = bout[0], oB = bout[0];
    #pragma unroll
    for (int i = 0; i < 64; ++i) {
        const float bi = b2[i];
        float a = bi, b = bi;
        #pragma unroll
        for (int k = 0; k < 64; ++k) {
            const float w = W2[i * 64 + k];
            a = fmaf(hA[k], w, a);
            b = fmaf(hB[k], w, b);
        }
        const float wo = Wout[i];
        oA = fmaf(silu_f(a), wo, oA);
        oB = fmaf(silu_f(b), wo, oB);
    }

    out[sA] = oA;
    out[sB] = oB;
}

// ---------------- Fallback: monolithic (if ws too small) ----------------
__global__ void __launch_bounds__(BLOCK)
hashgrid_mlp_kernel(const float* __restrict__ x,
                    const float* __restrict__ emb,
                    const float* __restrict__ W1,
                    const float* __restrict__ b1,
                    const float* __restrict__ W2,
                    const float* __restrict__ b2,
                    const float* __restrict__ Wout,
                    const float* __restrict__ bout,
                    float* __restrict__ out,
                    ResArr res)
{
    const int t = threadIdx.x;
    const int s = blockIdx.x * BLOCK + t;

    const float xn0 = (x[(size_t)s * 3 + 0] + 1.0f) * 0.5f;
    const float xn1 = (x[(size_t)s * 3 + 1] + 1.0f) * 0.5f;
    const float xn2 = (x[(size_t)s * 3 + 2] + 1.0f) * 0.5f;

    float enc[2 * NLEV];
    #pragma unroll
    for (int l = 0; l < NLEV; ++l) {
        const float rs = res.r[l];
        const float g0 = xn0 * rs, g1 = xn1 * rs, g2 = xn2 * rs;
        const float f0 = floorf(g0), f1 = floorf(g1), f2 = floorf(g2);
        const float w0 = g0 - f0, w1 = g1 - f1, w2 = g2 - f2;
        const uint32_t hb = (uint32_t)f0 + (uint32_t)f1 * P1 + (uint32_t)f2 * P2;
        const float2* tab = (const float2*)emb + (size_t)l * TBL;
        const float om0 = 1.0f - w0, om1 = 1.0f - w1, om2 = 1.0f - w2;
        float e0 = 0.0f, e1 = 0.0f;
        #pragma unroll
        for (int c = 0; c < 8; ++c) {
            const uint32_t cb0 = (c >> 2) & 1, cb1 = (c >> 1) & 1, cb2 = c & 1;
            uint32_t h = hb;
            if (cb0) h += 1u;
            if (cb1) h += P1;
            if (cb2) h += P2;
            h &= TMASK;
            const float2 vv = tab[h];
            float wt = (cb0 ? w0 : om0) * (cb1 ? w1 : om1);
            wt *= (cb2 ? w2 : om2);
            e0 = fmaf(wt, vv.x, e0);
            e1 = fmaf(wt, vv.y, e1);
        }
        enc[2 * l + 0] = e0;
        enc[2 * l + 1] = e1;
    }

    float h1[64];
    #pragma unroll
    for (int i = 0; i < 64; ++i) {
        float acc = b1[i];
        #pragma unroll
        for (int k = 0; k < 32; ++k)
            acc = fmaf(enc[k], W1[i * 32 + k], acc);
        h1[i] = silu_f(acc);
    }
    float o = bout[0];
    #pragma unroll
    for (int i = 0; i < 64; ++i) {
        float acc = b2[i];
        #pragma unroll
        for (int k = 0; k < 64; ++k)
            acc = fmaf(h1[k], W2[i * 64 + k], acc);
        o = fmaf(silu_f(acc), Wout[i], o);
    }
    out[s] = o;
}

extern "C" void kernel_launch(void* const* d_in, const int* in_sizes, int n_in,
                              void* d_out, int out_size, void* d_ws, size_t ws_size,
                              hipStream_t stream) {
    const float* x    = (const float*)d_in[0];
    const float* emb  = (const float*)d_in[1];
    const float* W1   = (const float*)d_in[2];
    const float* b1   = (const float*)d_in[3];
    const float* W2   = (const float*)d_in[4];
    const float* b2   = (const float*)d_in[5];
    const float* Wout = (const float*)d_in[6];
    const float* bout = (const float*)d_in[7];
    float* out = (float*)d_out;

    ResArr res;
    const double lg0 = log(16.0), lg1 = log(2048.0);
    for (int i = 0; i < NLEV; ++i)
        res.r[i] = (float)exp(lg0 + (lg1 - lg0) * (double)i / 15.0);

    const int n = in_sizes[0] / 3;                     // 262144 samples
    const size_t ws_needed = (size_t)n * NLEV * sizeof(float2);

    if (ws_size >= ws_needed) {
        float2* enc_ws = (float2*)d_ws;
        const int chunks = n / (BLOCK * SPT);          // 256
        dim3 gridA(2 * 8 * chunks);                    // 4096 blocks, phase-split
        encode_kernel<<<gridA, BLOCK, 0, stream>>>(x, emb, enc_ws, n, res);
        dim3 gridB(n / (BLOCK * MSPT));                // 512 blocks
        mlp_kernel<<<gridB, BLOCK, 0, stream>>>(enc_ws, W1, b1, W2, b2,
                                                Wout, bout, out, n);
    } else {
        dim3 grid(n / BLOCK);
        hashgrid_mlp_kernel<<<grid, BLOCK, 0, stream>>>(x, emb, W1, b1, W2, b2,
                                                        Wout, bout, out, res);
    }
}

// Round 7
// 160.567 us; speedup vs baseline: 1.6795x; 1.1860x over previous
//
#include <hip/hip_runtime.h>
#include <math.h>
#include <stdint.h>

#define NLEV 16
#define TBL 524288
#define TMASK (TBL - 1)
#define BLOCK 256
#define SPT 4            // samples per thread in encode
#define MSPT 2           // samples per thread in MLP
#define P1 2654435761u
#define P2 805459861u

struct ResArr { float r[NLEV]; };

typedef __attribute__((ext_vector_type(4))) float f32x4;
// 8B-aligned 16B load (table entries are float2-aligned; dwordx4 only needs dword align)
struct __attribute__((packed, aligned(8))) f4wrap { f32x4 v; };

__device__ __forceinline__ float silu_f(float v) {
    return __fdividef(v, 1.0f + __expf(-v));
}

// ---------------- Kernel A: hash-grid encode ----------------
// Phase-split level->XCD mapping (each XCD's L2 holds exactly one 4MB slice),
// corner pairing (dim0 hash coeff == 1 -> corners c,c+4 are adjacent entries:
// one dwordx4 covers both), SPT=4 samples/thread for 16 loads in flight.
__global__ void __launch_bounds__(BLOCK)
encode_kernel(const float* __restrict__ x,
              const float* __restrict__ emb,
              float2* __restrict__ enc_ws,
              int nsamp, ResArr res)
{
    const int bid  = blockIdx.x;
    const int half = gridDim.x >> 1;
    int lvl, chunk;
    if (bid < half) { lvl = bid & 7;               chunk = bid >> 3; }
    else            { lvl = 8 + ((bid - half) & 7); chunk = (bid - half) >> 3; }

    const int t  = threadIdx.x;
    const int s0 = chunk * (BLOCK * SPT) + t;
    const float rs = res.r[lvl];
    const float* tabf = emb + (size_t)lvl * TBL * 2;   // float view of level slice

    uint32_t i0[SPT][4];
    float w0[SPT], w1[SPT], w2[SPT];
    uint32_t bad = 0;

    #pragma unroll
    for (int p = 0; p < SPT; ++p) {
        const int s = s0 + p * BLOCK;
        const float xv0 = __builtin_nontemporal_load(&x[(size_t)s * 3 + 0]);
        const float xv1 = __builtin_nontemporal_load(&x[(size_t)s * 3 + 1]);
        const float xv2 = __builtin_nontemporal_load(&x[(size_t)s * 3 + 2]);
        const float g0 = (xv0 + 1.0f) * 0.5f * rs;
        const float g1 = (xv1 + 1.0f) * 0.5f * rs;
        const float g2 = (xv2 + 1.0f) * 0.5f * rs;
        const float f0 = floorf(g0), f1 = floorf(g1), f2 = floorf(g2);
        w0[p] = g0 - f0; w1[p] = g1 - f1; w2[p] = g2 - f2;
        const uint32_t hb = (uint32_t)f0 + (uint32_t)f1 * P1 + (uint32_t)f2 * P2;
        #pragma unroll
        for (int q = 0; q < 4; ++q) {     // q: (dim1,dim2) corner bits; dim0 paired
            uint32_t h = hb;
            if ((q >> 1) & 1) h += P1;
            if (q & 1)        h += P2;
            i0[p][q] = h & TMASK;
            bad |= (uint32_t)(i0[p][q] == TMASK);
        }
    }

    f32x4 v[SPT][4];
    if (__builtin_expect(__any((int)bad), 0)) {
        // rare wrap path: second entry of a pair is index 0
        #pragma unroll
        for (int p = 0; p < SPT; ++p)
            #pragma unroll
            for (int q = 0; q < 4; ++q) {
                const uint32_t a = i0[p][q];
                const uint32_t b = (a + 1u) & TMASK;
                const float2 lo = *(const float2*)(tabf + 2 * (size_t)a);
                const float2 hi = *(const float2*)(tabf + 2 * (size_t)b);
                v[p][q] = f32x4{lo.x, lo.y, hi.x, hi.y};
            }
    } else {
        // fast path: all 16 pair-loads independent & in flight together
        #pragma unroll
        for (int p = 0; p < SPT; ++p)
            #pragma unroll
            for (int q = 0; q < 4; ++q)
                v[p][q] = ((const f4wrap*)(tabf + 2 * (size_t)i0[p][q]))->v;
    }

    #pragma unroll
    for (int p = 0; p < SPT; ++p) {
        const float om0 = 1.0f - w0[p], om1 = 1.0f - w1[p], om2 = 1.0f - w2[p];
        float e0 = 0.0f, e1 = 0.0f;
        #pragma unroll
        for (int q = 0; q < 4; ++q) {
            float wb = (((q >> 1) & 1) ? w1[p] : om1) * ((q & 1) ? w2[p] : om2);
            const float c0 = om0 * wb;          // corner with dim0 bit = 0
            const float c1 = w0[p] * wb;        // corner with dim0 bit = 1
            e0 = fmaf(c0, v[p][q].x, fmaf(c1, v[p][q].z, e0));
            e1 = fmaf(c0, v[p][q].y, fmaf(c1, v[p][q].w, e1));
        }
        const int s = s0 + p * BLOCK;
        union { float2 f; unsigned long long u; } pk;
        pk.f.x = e0; pk.f.y = e1;
        __builtin_nontemporal_store(pk.u,
            (unsigned long long*)&enc_ws[(size_t)lvl * nsamp + s]);
    }
}

// ---------------- Kernel B: MLP 32 -> 64 -> 64 -> 1 ----------------
// Weights staged in LDS (25KB > 16KB scalar K$, so s_load path re-streams L2
// per wave; LDS broadcast reads are conflict-free and run on the DS pipe in
// parallel with VALU). MSPT=2 -> 16 wave-FMA-cycles per ds_read_b128 (12cyc).
__global__ void __launch_bounds__(BLOCK)
mlp_kernel(const float2* __restrict__ enc_ws,
           const float* __restrict__ W1,
           const float* __restrict__ b1,
           const float* __restrict__ W2,
           const float* __restrict__ b2,
           const float* __restrict__ Wout,
           const float* __restrict__ bout,
           float* __restrict__ out, int nsamp)
{
    __shared__ float sW1[64 * 32];
    __shared__ float sW2[64 * 64];
    __shared__ float sB1[64];
    __shared__ float sB2[64];
    __shared__ float sWo[64];
    __shared__ float sBo[1];

    const int t = threadIdx.x;

    // cooperative coalesced staging: W1 (512 float4) + W2 (1024 float4)
    {
        const float4* w1v = (const float4*)W1;
        float4* s1v = (float4*)sW1;
        #pragma unroll
        for (int i = 0; i < 2; ++i) s1v[t + i * BLOCK] = w1v[t + i * BLOCK];
        const float4* w2v = (const float4*)W2;
        float4* s2v = (float4*)sW2;
        #pragma unroll
        for (int i = 0; i < 4; ++i) s2v[t + i * BLOCK] = w2v[t + i * BLOCK];
        if (t < 64) {
            sB1[t] = b1[t];
            sB2[t] = b2[t];
            sWo[t] = Wout[t];
        }
        if (t == 0) sBo[0] = bout[0];
    }
    __syncthreads();

    const int sA = blockIdx.x * (BLOCK * MSPT) + t;
    const int sB = sA + BLOCK;

    float encA[2 * NLEV], encB[2 * NLEV];
    #pragma unroll
    for (int l = 0; l < NLEV; ++l) {
        const float2 va = enc_ws[(size_t)l * nsamp + sA];  // coalesced per level
        const float2 vb = enc_ws[(size_t)l * nsamp + sB];
        encA[2 * l] = va.x; encA[2 * l + 1] = va.y;
        encB[2 * l] = vb.x; encB[2 * l + 1] = vb.y;
    }

    float hA[64], hB[64];
    #pragma unroll
    for (int i = 0; i < 64; ++i) {
        const float bi = sB1[i];
        float a = bi, b = bi;
        #pragma unroll
        for (int k = 0; k < 32; k += 4) {
            const float4 w = *(const float4*)&sW1[i * 32 + k];  // ds_read_b128 broadcast
            a = fmaf(encA[k],     w.x, a); b = fmaf(encB[k],     w.x, b);
            a = fmaf(encA[k + 1], w.y, a); b = fmaf(encB[k + 1], w.y, b);
            a = fmaf(encA[k + 2], w.z, a); b = fmaf(encB[k + 2], w.z, b);
            a = fmaf(encA[k + 3], w.w, a); b = fmaf(encB[k + 3], w.w, b);
        }
        hA[i] = silu_f(a);
        hB[i] = silu_f(b);
    }

    float oA = sBo[0], oB = sBo[0];
    #pragma unroll
    for (int i = 0; i < 64; ++i) {
        const float bi = sB2[i];
        float a = bi, b = bi;
        #pragma unroll
        for (int k = 0; k < 64; k += 4) {
            const float4 w = *(const float4*)&sW2[i * 64 + k];
            a = fmaf(hA[k],     w.x, a); b = fmaf(hB[k],     w.x, b);
            a = fmaf(hA[k + 1], w.y, a); b = fmaf(hB[k + 1], w.y, b);
            a = fmaf(hA[k + 2], w.z, a); b = fmaf(hB[k + 2], w.z, b);
            a = fmaf(hA[k + 3], w.w, a); b = fmaf(hB[k + 3], w.w, b);
        }
        const float wo = sWo[i];
        oA = fmaf(silu_f(a), wo, oA);
        oB = fmaf(silu_f(b), wo, oB);
    }

    out[sA] = oA;
    out[sB] = oB;
}

// ---------------- Fallback: monolithic (if ws too small) ----------------
__global__ void __launch_bounds__(BLOCK)
hashgrid_mlp_kernel(const float* __restrict__ x,
                    const float* __restrict__ emb,
                    const float* __restrict__ W1,
                    const float* __restrict__ b1,
                    const float* __restrict__ W2,
                    const float* __restrict__ b2,
                    const float* __restrict__ Wout,
                    const float* __restrict__ bout,
                    float* __restrict__ out,
                    ResArr res)
{
    const int t = threadIdx.x;
    const int s = blockIdx.x * BLOCK + t;

    const float xn0 = (x[(size_t)s * 3 + 0] + 1.0f) * 0.5f;
    const float xn1 = (x[(size_t)s * 3 + 1] + 1.0f) * 0.5f;
    const float xn2 = (x[(size_t)s * 3 + 2] + 1.0f) * 0.5f;

    float enc[2 * NLEV];
    #pragma unroll
    for (int l = 0; l < NLEV; ++l) {
        const float rs = res.r[l];
        const float g0 = xn0 * rs, g1 = xn1 * rs, g2 = xn2 * rs;
        const float f0 = floorf(g0), f1 = floorf(g1), f2 = floorf(g2);
        const float w0 = g0 - f0, w1 = g1 - f1, w2 = g2 - f2;
        const uint32_t hb = (uint32_t)f0 + (uint32_t)f1 * P1 + (uint32_t)f2 * P2;
        const float2* tab = (const float2*)emb + (size_t)l * TBL;
        const float om0 = 1.0f - w0, om1 = 1.0f - w1, om2 = 1.0f - w2;
        float e0 = 0.0f, e1 = 0.0f;
        #pragma unroll
        for (int c = 0; c < 8; ++c) {
            const uint32_t cb0 = (c >> 2) & 1, cb1 = (c >> 1) & 1, cb2 = c & 1;
            uint32_t h = hb;
            if (cb0) h += 1u;
            if (cb1) h += P1;
            if (cb2) h += P2;
            h &= TMASK;
            const float2 vv = tab[h];
            float wt = (cb0 ? w0 : om0) * (cb1 ? w1 : om1);
            wt *= (cb2 ? w2 : om2);
            e0 = fmaf(wt, vv.x, e0);
            e1 = fmaf(wt, vv.y, e1);
        }
        enc[2 * l + 0] = e0;
        enc[2 * l + 1] = e1;
    }

    float h1[64];
    #pragma unroll
    for (int i = 0; i < 64; ++i) {
        float acc = b1[i];
        #pragma unroll
        for (int k = 0; k < 32; ++k)
            acc = fmaf(enc[k], W1[i * 32 + k], acc);
        h1[i] = silu_f(acc);
    }
    float o = bout[0];
    #pragma unroll
    for (int i = 0; i < 64; ++i) {
        float acc = b2[i];
        #pragma unroll
        for (int k = 0; k < 64; ++k)
            acc = fmaf(h1[k], W2[i * 64 + k], acc);
        o = fmaf(silu_f(acc), Wout[i], o);
    }
    out[s] = o;
}

extern "C" void kernel_launch(void* const* d_in, const int* in_sizes, int n_in,
                              void* d_out, int out_size, void* d_ws, size_t ws_size,
                              hipStream_t stream) {
    const float* x    = (const float*)d_in[0];
    const float* emb  = (const float*)d_in[1];
    const float* W1   = (const float*)d_in[2];
    const float* b1   = (const float*)d_in[3];
    const float* W2   = (const float*)d_in[4];
    const float* b2   = (const float*)d_in[5];
    const float* Wout = (const float*)d_in[6];
    const float* bout = (const float*)d_in[7];
    float* out = (float*)d_out;

    ResArr res;
    const double lg0 = log(16.0), lg1 = log(2048.0);
    for (int i = 0; i < NLEV; ++i)
        res.r[i] = (float)exp(lg0 + (lg1 - lg0) * (double)i / 15.0);

    const int n = in_sizes[0] / 3;                     // 262144 samples
    const size_t ws_needed = (size_t)n * NLEV * sizeof(float2);

    if (ws_size >= ws_needed) {
        float2* enc_ws = (float2*)d_ws;
        const int chunks = n / (BLOCK * SPT);          // 256
        dim3 gridA(2 * 8 * chunks);                    // 4096 blocks, phase-split
        encode_kernel<<<gridA, BLOCK, 0, stream>>>(x, emb, enc_ws, n, res);
        dim3 gridB(n / (BLOCK * MSPT));                // 512 blocks
        mlp_kernel<<<gridB, BLOCK, 0, stream>>>(enc_ws, W1, b1, W2, b2,
                                                Wout, bout, out, n);
    } else {
        dim3 grid(n / BLOCK);
        hashgrid_mlp_kernel<<<grid, BLOCK, 0, stream>>>(x, emb, W1, b1, W2, b2,
                                                        Wout, bout, out, res);
    }
}